// Round 3
// baseline (1337.484 us; speedup 1.0000x reference)
//
#include <hip/hip_runtime.h>
#include <hip/hip_bf16.h>

typedef __hip_bfloat16 bf16;
typedef __attribute__((ext_vector_type(8))) short bf16x8s;
typedef __attribute__((ext_vector_type(4))) float f32x4;

#define NB 64
#define NS 32
#define NV 10000
#define NE 512
#define NH 512
#define NF 2048
#define ND 1024
#define G_WGS 32

static __device__ __forceinline__ float bf2f(bf16 x) { return __bfloat162float(x); }
static __device__ __forceinline__ bf16 f2bf(float x) { return __float2bfloat16(x); }
static __device__ __forceinline__ f32x4 mfma16(bf16x8s a, bf16x8s b, f32x4 c) {
  return __builtin_amdgcn_mfma_f32_16x16x32_bf16(a, b, c, 0, 0, 0);
}

// One 16x16 output tile per wave. A row-major bf16 [*, lda], BT row-major bf16 [N][K].
// mfma_f32_16x16x32_bf16 fragment layout:
//   A: row = lane&15, k = (lane>>4)*8 + j ; B: col = lane&15, same k
//   C/D: col = lane&15, row = (lane>>4)*4 + j   [measured: learn_hip m89]
__device__ __forceinline__ f32x4 wave_tile16(const bf16* A, const bf16* BT,
                                             int lda, int K, int m0, int n0) {
  int lane = threadIdx.x & 63;
  int r = lane & 15, g = lane >> 4;
  const bf16* ap = A + (size_t)(m0 + r) * lda + g * 8;
  const bf16* bp = BT + (size_t)(n0 + r) * K + g * 8;
  f32x4 acc = {0.f, 0.f, 0.f, 0.f};
#pragma unroll 4
  for (int k = 0; k < K; k += 32) {
    bf16x8s a = *(const bf16x8s*)(ap + k);
    bf16x8s b = *(const bf16x8s*)(bp + k);
    acc = mfma16(a, b, acc);
  }
  return acc;
}

// ---------------- embedding gather + f32->bf16 ----------------
__global__ void k_embed(const int* __restrict__ tokens, const float* __restrict__ emb,
                        bf16* __restrict__ x0) {
  int row = blockIdx.x;            // 0..2047
  int tok = tokens[row];
  const float2* src = (const float2*)(emb + (size_t)tok * NE);
  uint32_t* dst = (uint32_t*)(x0 + (size_t)row * NE);
  float2 v = src[threadIdx.x];
  __hip_bfloat162 p;
  p.x = f2bf(v.x); p.y = f2bf(v.y);
  dst[threadIdx.x] = *(uint32_t*)&p;
}

// ---------------- f32->bf16 convert (contiguous) ----------------
__global__ void k_cvt(const float* __restrict__ src, bf16* __restrict__ dst, int n) {
  int i = blockIdx.x * 256 + threadIdx.x;
  if (i < n) dst[i] = f2bf(src[i]);
}

// ---------------- transpose + f32->bf16: dst[n][k] = bf16(src[k][n]) ----------------
__global__ void k_transpose(const float* __restrict__ src, bf16* __restrict__ dst,
                            int K, int N) {
  __shared__ float tile[32][33];
  int n0 = blockIdx.x * 32, k0 = blockIdx.y * 32;
  int tx = threadIdx.x & 31, ty = threadIdx.x >> 5;   // 32x8
  for (int i = ty; i < 32; i += 8) {
    int k = k0 + i, n = n0 + tx;
    tile[i][tx] = (k < K && n < N) ? src[(size_t)k * N + n] : 0.f;
  }
  __syncthreads();
  for (int i = ty; i < 32; i += 8) {
    int n = n0 + i, k = k0 + tx;
    if (n < N && k < K) dst[(size_t)n * K + k] = f2bf(tile[tx][i]);
  }
}

// ---------------- fused 12x [512,512] layer-weight transposes ----------------
// z = l*6 + q; q: 0=wr_h->ruhT, 1=wu_h->ruhT+512*512, 2=wh_h->hhT,
//                 3=wr_x->xT, 4=wu_x->xT+512*512, 5=wh_x->xT+1024*512
__global__ void k_transpose12(const float* __restrict__ w_r, const float* __restrict__ w_u,
                              const float* __restrict__ w_h, bf16* __restrict__ ruhT,
                              bf16* __restrict__ hhT, bf16* __restrict__ xT) {
  int z = blockIdx.z, l = z / 6, q = z % 6;
  const float* srcs[6] = {
    w_r + (size_t)l * ND * NH + (size_t)512 * NH,
    w_u + (size_t)l * ND * NH + (size_t)512 * NH,
    w_h + (size_t)l * ND * NH + (size_t)512 * NH,
    w_r + (size_t)l * ND * NH,
    w_u + (size_t)l * ND * NH,
    w_h + (size_t)l * ND * NH };
  bf16* dsts[6] = {
    ruhT + (size_t)l * 1024 * 512,
    ruhT + (size_t)l * 1024 * 512 + 512 * 512,
    hhT  + (size_t)l * 512 * 512,
    xT   + (size_t)l * 1536 * 512,
    xT   + (size_t)l * 1536 * 512 + 512 * 512,
    xT   + (size_t)l * 1536 * 512 + 1024 * 512 };
  const float* src = srcs[q];
  bf16* dst = dsts[q];
  __shared__ float tile[32][33];
  int n0 = blockIdx.x * 32, k0 = blockIdx.y * 32;
  int tx = threadIdx.x & 31, ty = threadIdx.x >> 5;
  for (int i = ty; i < 32; i += 8)
    tile[i][tx] = src[(size_t)(k0 + i) * NH + n0 + tx];
  __syncthreads();
  for (int i = ty; i < 32; i += 8)
    dst[(size_t)(n0 + i) * NH + k0 + tx] = f2bf(tile[tx][i]);
}

// ---------------- both layers' gate biases -> bias3[2][1536] f32 ----------------
__global__ void k_bias3all(const float* __restrict__ br, const float* __restrict__ bu,
                           const float* __restrict__ bh, float* __restrict__ bias) {
  int i = blockIdx.x * 256 + threadIdx.x;
  if (i < 3072) {
    int l = i / 1536, c = i % 1536;
    const float* s = (c < 512) ? (br + l * 512 + c)
                   : (c < 1024 ? (bu + l * 512 + (c - 512)) : (bh + l * 512 + (c - 1024)));
    bias[i] = *s;
  }
}

// ---------------- h0 = cnn @ w_in + b_in : [64,2048]@[2048,512], dual-store ------------
__global__ void k_gemm_h0(const bf16* __restrict__ A, const bf16* __restrict__ BT,
                          const float* __restrict__ bias,
                          float* __restrict__ h0f, bf16* __restrict__ h0b) {
  int wid = blockIdx.x * 4 + (threadIdx.x >> 6);  // 128 waves: 4 x 32 tiles
  int mt = wid & 3, nt = wid >> 2;
  f32x4 acc = wave_tile16(A, BT, NF, NF, mt * 16, nt * 16);
  int lane = threadIdx.x & 63;
  int cl = lane & 15, g = lane >> 4;
  int col = nt * 16 + cl;
  float bv = bias[col];
#pragma unroll
  for (int j = 0; j < 4; j++) {
    int row = mt * 16 + g * 4 + j;
    float v = acc[j] + bv;
    h0f[(size_t)row * NH + col] = v;
    h0b[(size_t)row * NH + col] = f2bf(v);
  }
}

// ---------------- pre = X @ Wx_cat + bias3 : [2048,512]@[512,1536] -> f32 ----------------
__global__ void k_gemm_pre(const bf16* __restrict__ A, const bf16* __restrict__ BT,
                           const float* __restrict__ bias, float* __restrict__ pre) {
  int wid = (blockIdx.x * blockDim.x + threadIdx.x) >> 6;  // 12288 waves: 128 x 96 tiles
  int mt = wid % 128, nt = wid / 128;
  f32x4 acc = wave_tile16(A, BT, NE, NE, mt * 16, nt * 16);
  int lane = threadIdx.x & 63;
  int cl = lane & 15, g = lane >> 4;
  int col = nt * 16 + cl;
  float bv = bias[col];
#pragma unroll
  for (int j = 0; j < 4; j++) {
    int row = mt * 16 + g * 4 + j;
    pre[(size_t)row * 1536 + col] = acc[j] + bv;
  }
}

// ---------------- device-wide spin barrier (monotonic epoch counter) ----------------
__device__ __forceinline__ void gbar(unsigned* cnt, unsigned ep) {
  __syncthreads();
  if (threadIdx.x == 0) {
    __threadfence();                       // release: publish this WG's writes
    atomicAdd(cnt, 1u);                    // device-scope arrive
    while (__hip_atomic_load(cnt, __ATOMIC_RELAXED, __HIP_MEMORY_SCOPE_AGENT) < G_WGS * ep)
      __builtin_amdgcn_s_sleep(1);
    __threadfence();                       // acquire: invalidate stale caches
  }
  __syncthreads();
}

// ---------------- persistent per-layer GRU recurrence ----------------
// 32 WGs x 512 thr = 256 waves, all co-resident (1 block/CU max).
// Phase1 (256 tiles): gates r,u over [64,1024]; Phase2 (128 tiles): h_tilde+combine.
// W fragments register-resident across all 32 steps (16KB/wave each phase).
__global__ __launch_bounds__(512, 1)
void k_gru_layer(const bf16* __restrict__ W_ruh_T, const bf16* __restrict__ W_hh_T,
                 const float* __restrict__ pre,
                 float* __restrict__ hf, bf16* __restrict__ hb,
                 bf16* __restrict__ rh, float* __restrict__ u_buf,
                 bf16* __restrict__ seq, unsigned* __restrict__ barcnt) {
  const int lane = threadIdx.x & 63;
  const int w = blockIdx.x * 8 + (threadIdx.x >> 6);   // 0..255
  const int cl = lane & 15, g = lane >> 4;
  const int mt = w & 3, nt = w >> 2;                   // phase1 tile (nt 0..63)
  const int col = nt * 16 + cl;

  // preload W_ruh_T B-fragments: 16 cols x K512 -> 64 VGPR, reused all steps
  bf16x8s bw1[16];
  {
    const bf16* bp = W_ruh_T + (size_t)(nt * 16 + cl) * NH + g * 8;
#pragma unroll
    for (int k = 0; k < 16; k++) bw1[k] = *(const bf16x8s*)(bp + k * 32);
  }
  bf16x8s bw2[16];
  if (w < 128) {                                       // phase2 tile = same (mt,nt), nt<32
    const bf16* bp = W_hh_T + (size_t)(nt * 16 + cl) * NH + g * 8;
#pragma unroll
    for (int k = 0; k < 16; k++) bw2[k] = *(const bf16x8s*)(bp + k * 32);
  }

  unsigned ep = 0;
  for (int t = 0; t < NS; t++) {
    { // ---- phase 1: r (col<512) / u (col>=512) gates
      const bf16* ap = hb + (size_t)(mt * 16 + cl) * NH + g * 8;
      f32x4 acc0 = {0.f,0.f,0.f,0.f}, acc1 = {0.f,0.f,0.f,0.f};
#pragma unroll
      for (int k = 0; k < 16; k += 2) {
        acc0 = mfma16(*(const bf16x8s*)(ap + k * 32),       bw1[k],     acc0);
        acc1 = mfma16(*(const bf16x8s*)(ap + (k + 1) * 32), bw1[k + 1], acc1);
      }
#pragma unroll
      for (int j = 0; j < 4; j++) {
        int b = mt * 16 + g * 4 + j;
        float pv = pre[(size_t)(b * NS + t) * 1536 + col];
        float gate = 1.f / (1.f + expf(-(acc0[j] + acc1[j] + pv)));
        if (col < 512) rh[b * NH + col] = f2bf(gate * hf[b * NH + col]);
        else           u_buf[b * NH + (col - 512)] = gate;
      }
    }
    gbar(barcnt, ++ep);
    if (w < 128) { // ---- phase 2: h_tilde + combine (col = nt*16+cl < 512 here)
      const bf16* ap = rh + (size_t)(mt * 16 + cl) * NH + g * 8;
      f32x4 acc0 = {0.f,0.f,0.f,0.f}, acc1 = {0.f,0.f,0.f,0.f};
#pragma unroll
      for (int k = 0; k < 16; k += 2) {
        acc0 = mfma16(*(const bf16x8s*)(ap + k * 32),       bw2[k],     acc0);
        acc1 = mfma16(*(const bf16x8s*)(ap + (k + 1) * 32), bw2[k + 1], acc1);
      }
#pragma unroll
      for (int j = 0; j < 4; j++) {
        int b = mt * 16 + g * 4 + j;
        float pv = pre[(size_t)(b * NS + t) * 1536 + 1024 + col];
        float htil = tanhf(acc0[j] + acc1[j] + pv);
        float u = u_buf[b * NH + col];
        float hold = hf[b * NH + col];
        float hnew = hold * u + (1.f - u) * htil;
        hf[b * NH + col] = hnew;
        hb[b * NH + col] = f2bf(hnew);
        seq[(size_t)(b * NS + t) * NH + col] = f2bf(hnew);
      }
    }
    gbar(barcnt, ++ep);
  }
}

// ---------------- logits = seq1 @ w_out + b_out : [2048,512]@[512,10000] -> f32 ---------
__global__ void k_gemm_out(const bf16* __restrict__ A, const bf16* __restrict__ BT,
                           const float* __restrict__ bias, float* __restrict__ out) {
  int wid = blockIdx.x * 4 + (threadIdx.x >> 6);  // 32 * 157 = 5024 waves
  int mg = wid % 32, ng = wid / 32;
  int lane = threadIdx.x & 63;
  int cl = lane & 15, g = lane >> 4;
  f32x4 acc[4][4] = {};
  const bf16* a0 = A + (size_t)(mg * 64 + cl) * NE + g * 8;
  const bf16* b0 = BT + (size_t)(ng * 64 + cl) * NE + g * 8;
#pragma unroll 2
  for (int k = 0; k < NE; k += 32) {
    bf16x8s av[4], bv[4];
#pragma unroll
    for (int i = 0; i < 4; i++) av[i] = *(const bf16x8s*)(a0 + (size_t)(i * 16) * NE + k);
#pragma unroll
    for (int i = 0; i < 4; i++) bv[i] = *(const bf16x8s*)(b0 + (size_t)(i * 16) * NE + k);
#pragma unroll
    for (int mi = 0; mi < 4; mi++)
#pragma unroll
      for (int ni = 0; ni < 4; ni++)
        acc[mi][ni] = mfma16(av[mi], bv[ni], acc[mi][ni]);
  }
#pragma unroll
  for (int mi = 0; mi < 4; mi++) {
#pragma unroll
    for (int ni = 0; ni < 4; ni++) {
      int colb = ng * 64 + ni * 16 + cl;
      if (colb < NV) {
        float bv2 = bias[colb];
#pragma unroll
        for (int j = 0; j < 4; j++) {
          int row = mg * 64 + mi * 16 + g * 4 + j;
          out[(size_t)row * NV + colb] = acc[mi][ni][j] + bv2;
        }
      }
    }
  }
}

extern "C" void kernel_launch(void* const* d_in, const int* in_sizes, int n_in,
                              void* d_out, int out_size, void* d_ws, size_t ws_size,
                              hipStream_t stream) {
  const int*   tokens = (const int*)d_in[0];
  const float* cnn    = (const float*)d_in[1];
  const float* emb    = (const float*)d_in[2];
  const float* w_in   = (const float*)d_in[3];
  const float* b_in   = (const float*)d_in[4];
  const float* w_r    = (const float*)d_in[5];
  const float* b_r    = (const float*)d_in[6];
  const float* w_u    = (const float*)d_in[7];
  const float* b_u    = (const float*)d_in[8];
  const float* w_h    = (const float*)d_in[9];
  const float* b_h    = (const float*)d_in[10];
  const float* w_out  = (const float*)d_in[11];
  const float* b_out  = (const float*)d_in[12];
  float* out = (float*)d_out;

  // ---- workspace carve-up (bytes), 256B aligned ----
  char* ws = (char*)d_ws;
  size_t off = 0;
  auto alloc = [&](size_t bytes) { char* p = ws + off; off += (bytes + 255) & ~(size_t)255; return p; };
  bf16*  x0      = (bf16*) alloc((size_t)2048 * 512 * 2);
  bf16*  seq0    = (bf16*) alloc((size_t)2048 * 512 * 2);
  bf16*  seq1    = (bf16*) alloc((size_t)2048 * 512 * 2);
  float* pre     = (float*)alloc((size_t)2048 * 1536 * 4);
  float* h0f     = (float*)alloc((size_t)64 * 512 * 4);
  bf16*  h0b     = (bf16*) alloc((size_t)64 * 512 * 2);
  float* hf      = (float*)alloc((size_t)64 * 512 * 4);
  bf16*  hb      = (bf16*) alloc((size_t)64 * 512 * 2);
  bf16*  rh      = (bf16*) alloc((size_t)64 * 512 * 2);
  float* u_buf   = (float*)alloc((size_t)64 * 512 * 4);
  float* bias3   = (float*)alloc((size_t)2 * 1536 * 4);
  bf16*  cnn_b   = (bf16*) alloc((size_t)64 * 2048 * 2);
  bf16*  w_in_T  = (bf16*) alloc((size_t)512 * 2048 * 2);
  bf16*  w_ruh_T = (bf16*) alloc((size_t)2 * 1024 * 512 * 2);   // per layer: [1024][512]
  bf16*  w_hh_T  = (bf16*) alloc((size_t)2 * 512 * 512 * 2);    // per layer: [512][512]
  bf16*  w_x_T   = (bf16*) alloc((size_t)2 * 1536 * 512 * 2);   // per layer: [1536][512]
  bf16*  w_out_T = (bf16*) alloc((size_t)10048 * 512 * 2);      // padded to 10048 rows
  unsigned* barcnt = (unsigned*)alloc(256);                     // [0]=layer0, [1]=layer1
  (void)ws_size; (void)in_sizes; (void)n_in; (void)out_size;

  // zero barrier counters + w_out_T pad rows
  hipMemsetAsync(barcnt, 0, 256, stream);
  hipMemsetAsync(w_out_T + (size_t)10000 * 512, 0, (size_t)48 * 512 * 2, stream);

  // ---- embedding gather (+convert) ----
  k_embed<<<2048, 256, 0, stream>>>(tokens, emb, x0);

  // ---- input converts / weight transposes (f32 -> bf16) ----
  k_cvt<<<512, 256, 0, stream>>>(cnn, cnn_b, 64 * 2048);
  k_transpose<<<dim3(16, 64), 256, 0, stream>>>(w_in, w_in_T, NF, NH);   // [2048,512]->[512][2048]
  k_transpose12<<<dim3(16, 16, 12), 256, 0, stream>>>(w_r, w_u, w_h, w_ruh_T, w_hh_T, w_x_T);
  k_transpose<<<dim3(313, 16), 256, 0, stream>>>(w_out, w_out_T, 512, NV);
  k_bias3all<<<12, 256, 0, stream>>>(b_r, b_u, b_h, bias3);

  // ---- h0 ----
  k_gemm_h0<<<32, 256, 0, stream>>>(cnn_b, w_in_T, b_in, h0f, h0b);

  // ---- per-layer: x-part GEMM, then fused persistent recurrence ----
  const bf16* seq_in[2] = {x0, seq0};
  bf16* seq_out[2] = {seq0, seq1};
  for (int l = 0; l < 2; l++) {
    k_gemm_pre<<<3072, 256, 0, stream>>>(seq_in[l], w_x_T + (size_t)l * 1536 * 512,
                                         bias3 + (size_t)l * 1536, pre);
    hipMemcpyAsync(hf, h0f, (size_t)64 * 512 * 4, hipMemcpyDeviceToDevice, stream);
    hipMemcpyAsync(hb, h0b, (size_t)64 * 512 * 2, hipMemcpyDeviceToDevice, stream);
    k_gru_layer<<<G_WGS, 512, 0, stream>>>(w_ruh_T + (size_t)l * 1024 * 512,
                                           w_hh_T + (size_t)l * 512 * 512,
                                           pre, hf, hb, rh, u_buf, seq_out[l], barcnt + l);
  }

  // ---- logits ----
  k_gemm_out<<<1256, 256, 0, stream>>>(seq1, w_out_T, b_out, out);
}